// Round 1
// baseline (1003.945 us; speedup 1.0000x reference)
//
#include <hip/hip_runtime.h>
#include <cstdint>
#include <cstddef>

#define B_ 16
#define C_ 256
#define T_ 128
#define V_ 64
#define K_ 8
#define O_ 256
#define TN 8192      /* T_*V_ */
#define NBT 131072   /* B_*T_*V_ : BN sample count */

/* ---- workspace layout (float offsets) ---- */
#define OFF_TP     0          /* [B][C][V]        262144 */
#define OFF_X1     262144     /* [B][O][V]        262144 */
#define OFF_X2     524288     /* [B][O][V]        262144 */
#define OFF_ADA    786432     /* [B][K][V][V]     524288 */
#define OFF_STATS  1310720    /* stem_sum,stem_sumsq,head_sum,head_sumsq : 4*256 */
#define OFF_SSC    1311744    /* stem scale[256], shift[256] */
#define OFF_HSC    1312256    /* head scale[256], shift[256] */
#define OFF_Z      1312768    /* [B][O][T][V]   33554432 */
#define OFF_H2     34867200   /* [B][O][T][V]   33554432 */
/* total = 68421632 floats = 273.7 MB */

/* tp[b,c,v] = mean_t x[b,c,t,v] */
__global__ __launch_bounds__(256) void k_mean_t(const float* __restrict__ x,
                                                float* __restrict__ tp) {
    int i4 = blockIdx.x * 256 + threadIdx.x;   /* 65536 float4 outputs */
    int v4 = i4 & 15;
    int c  = (i4 >> 4) & 255;
    int b  = i4 >> 12;
    const float4* px = (const float4*)(x + (size_t)(b * C_ + c) * T_ * V_) + v4;
    float4 s = {0.f, 0.f, 0.f, 0.f};
    for (int t = 0; t < T_; t++) {
        float4 v = px[t * 16];
        s.x += v.x; s.y += v.y; s.z += v.z; s.w += v.w;
    }
    const float r = 1.0f / (float)T_;
    s.x *= r; s.y *= r; s.z *= r; s.w *= r;
    ((float4*)(tp + (size_t)(b * C_ + c) * V_))[v4] = s;
}

/* x1[b,o,v] = sum_c tp[b,c,v]*w1[o,c] + b1[o]; same for x2 */
__global__ __launch_bounds__(256) void k_x1x2(const float* __restrict__ tp,
                                              const float* __restrict__ w1, const float* __restrict__ b1,
                                              const float* __restrict__ w2, const float* __restrict__ b2,
                                              float* __restrict__ x1, float* __restrict__ x2) {
    int i4 = blockIdx.x * 256 + threadIdx.x;   /* 65536 */
    int v4 = i4 & 15;
    int o  = (i4 >> 4) & 255;
    int b  = i4 >> 12;
    const float4* ptp = (const float4*)(tp + (size_t)b * C_ * V_) + v4;
    float4 s1 = {0.f,0.f,0.f,0.f}, s2 = {0.f,0.f,0.f,0.f};
    for (int c = 0; c < C_; c++) {
        float4 tv = ptp[c * 16];
        float wa = w1[o * C_ + c];
        float wb = w2[o * C_ + c];
        s1.x += tv.x * wa; s1.y += tv.y * wa; s1.z += tv.z * wa; s1.w += tv.w * wa;
        s2.x += tv.x * wb; s2.y += tv.y * wb; s2.z += tv.z * wb; s2.w += tv.w * wb;
    }
    float bv1 = b1[o], bv2 = b2[o];
    s1.x += bv1; s1.y += bv1; s1.z += bv1; s1.w += bv1;
    s2.x += bv2; s2.y += bv2; s2.z += bv2; s2.w += bv2;
    ((float4*)(x1 + (size_t)(b * O_ + o) * V_))[v4] = s1;
    ((float4*)(x2 + (size_t)(b * O_ + o) * V_))[v4] = s2;
}

/* ada[b,k,v,w] = softmax_v( sum_c x1[b,k,c,v]*x2[b,k,c,w] )   one wave per (b,k,w) */
__global__ __launch_bounds__(64) void k_ada(const float* __restrict__ x1,
                                            const float* __restrict__ x2,
                                            float* __restrict__ ada) {
    int bid = blockIdx.x;            /* 8192 = B*K*V */
    int w = bid & 63;
    int k = (bid >> 6) & 7;
    int b = bid >> 9;
    int v = threadIdx.x;
    const float* p1 = x1 + ((size_t)b * O_ + k * 32) * V_;
    const float* p2 = x2 + ((size_t)b * O_ + k * 32) * V_;
    float s = 0.f;
    #pragma unroll
    for (int c = 0; c < 32; c++) s += p1[c * V_ + v] * p2[c * V_ + w];
    float m = s;
    #pragma unroll
    for (int off = 32; off >= 1; off >>= 1) m = fmaxf(m, __shfl_xor(m, off, 64));
    float e = __expf(s - m);
    float sum = e;
    #pragma unroll
    for (int off = 32; off >= 1; off >>= 1) sum += __shfl_xor(sum, off, 64);
    ada[((size_t)(b * K_ + k) * V_ + v) * V_ + w] = e / sum;
}

/* out[b,o,n] = sum_c w[o,c]*in[b,c,n] + bias[o]; accumulates per-o sum/sumsq.
   grid (TN/128, O/64, B), 256 threads; tile 64o x 128n, K-chunk 32 */
__global__ __launch_bounds__(256) void k_gemm_stats(const float* __restrict__ in,
                                                    const float* __restrict__ w,
                                                    const float* __restrict__ bias,
                                                    float* __restrict__ out,
                                                    float* __restrict__ psum,
                                                    float* __restrict__ psumsq) {
    __shared__ float xs[32][128];
    __shared__ float wsT[32][68];   /* [cc][o], stride 68: aligned f4 reads, mild store conflict */
    int t  = threadIdx.x;
    int n0 = blockIdx.x * 128;
    int o0 = blockIdx.y * 64;
    int b  = blockIdx.z;
    const float* inb = in + (size_t)b * C_ * TN;
    int ng = t & 31;        /* n = n0 + ng*4 + j */
    int og = t >> 5;        /* o = o0 + og*8 + i */
    float acc[8][4] = {};
    for (int c0 = 0; c0 < C_; c0 += 32) {
        #pragma unroll
        for (int i = 0; i < 4; i++) {
            int e = t + i * 256;            /* f4 idx 0..1023 */
            int kk = e >> 5, c4 = e & 31;
            float4 vv = *(const float4*)(inb + (size_t)(c0 + kk) * TN + n0 + c4 * 4);
            *(float4*)&xs[kk][c4 * 4] = vv;
        }
        #pragma unroll
        for (int i = 0; i < 8; i++) {
            int e = t + i * 256;            /* 0..2047 */
            int cc = e & 31, oo = e >> 5;
            wsT[cc][oo] = w[(size_t)(o0 + oo) * C_ + c0 + cc];
        }
        __syncthreads();
        #pragma unroll
        for (int kk = 0; kk < 32; kk++) {
            float4 xv = *(const float4*)&xs[kk][ng * 4];
            float4 wa = *(const float4*)&wsT[kk][og * 8];
            float4 wb = *(const float4*)&wsT[kk][og * 8 + 4];
            float xr[4] = {xv.x, xv.y, xv.z, xv.w};
            float wr[8] = {wa.x, wa.y, wa.z, wa.w, wb.x, wb.y, wb.z, wb.w};
            #pragma unroll
            for (int i = 0; i < 8; i++)
                #pragma unroll
                for (int j = 0; j < 4; j++)
                    acc[i][j] += wr[i] * xr[j];
        }
        __syncthreads();
    }
    float* outb = out + (size_t)b * O_ * TN;
    float ls[8], lss[8];
    #pragma unroll
    for (int i = 0; i < 8; i++) {
        int o = o0 + og * 8 + i;
        float bv = bias[o];
        float4 r = {acc[i][0] + bv, acc[i][1] + bv, acc[i][2] + bv, acc[i][3] + bv};
        *(float4*)(outb + (size_t)o * TN + n0 + ng * 4) = r;
        ls[i]  = r.x + r.y + r.z + r.w;
        lss[i] = r.x * r.x + r.y * r.y + r.z * r.z + r.w * r.w;
    }
    /* reduce over the 32 lanes that share this og (xor<=16 stays in the half) */
    #pragma unroll
    for (int off = 16; off >= 1; off >>= 1) {
        #pragma unroll
        for (int i = 0; i < 8; i++) {
            ls[i]  += __shfl_xor(ls[i],  off, 64);
            lss[i] += __shfl_xor(lss[i], off, 64);
        }
    }
    if (ng == 0) {
        #pragma unroll
        for (int i = 0; i < 8; i++) {
            int o = o0 + og * 8 + i;
            atomicAdd(&psum[o],   ls[i]);
            atomicAdd(&psumsq[o], lss[i]);
        }
    }
}

__global__ void k_finalize(const float* __restrict__ psum, const float* __restrict__ psumsq,
                           const float* __restrict__ gamma, const float* __restrict__ betap,
                           float* __restrict__ scale, float* __restrict__ shift) {
    int o = threadIdx.x;
    float mean = psum[o]   * (1.0f / (float)NBT);
    float var  = psumsq[o] * (1.0f / (float)NBT) - mean * mean;
    float sc = gamma[o] * rsqrtf(var + 1e-5f);
    scale[o] = sc;
    shift[o] = betap[o] - mean * sc;
}

/* h2[b, k*32+c, t, w] = sum_v relu(bn(z[b,k*32+c,t,v])) * A[b,k,c,v,w]
   A built on the fly. One block per (b,k,c). */
__global__ __launch_bounds__(256) void k_einsum(const float* __restrict__ z,
                                                const float* __restrict__ x1,
                                                const float* __restrict__ x2,
                                                const float* __restrict__ ada,
                                                const float* __restrict__ A_param,
                                                const float* __restrict__ alphap,
                                                const float* __restrict__ betap,
                                                const float* __restrict__ scale,
                                                const float* __restrict__ shift,
                                                float* __restrict__ h2) {
    __shared__ float As[64][64];
    __shared__ float Hs[128][68];   /* stride 68: aligned f4, conflict-free with row=tg+16i */
    __shared__ float x1s[64], x2s[64];
    int t = threadIdx.x;
    int c = blockIdx.x & 31;
    int k = (blockIdx.x >> 5) & 7;
    int b = blockIdx.x >> 8;
    int o1 = k * 32 + c;
    float alpha = alphap[0], beta = betap[0];
    if (t < 64)        x1s[t]      = x1[((size_t)b * O_ + o1) * V_ + t];
    else if (t < 128)  x2s[t - 64] = x2[((size_t)b * O_ + o1) * V_ + (t - 64)];
    __syncthreads();
    const float* adab = ada + (size_t)(b * K_ + k) * V_ * V_;
    const float* Apb  = A_param + (size_t)k * V_ * V_;
    #pragma unroll
    for (int i = 0; i < 16; i++) {
        int e = t + i * 256;            /* e = v*64 + w */
        int v = e >> 6, w = e & 63;
        As[v][w] = Apb[e] + alpha * tanhf(x1s[v] - x2s[w]) + beta * adab[e];
    }
    float sc = scale[o1], sh = shift[o1];
    const float* zb = z + ((size_t)b * O_ + o1) * TN;
    #pragma unroll
    for (int i = 0; i < 8; i++) {
        int e = t + i * 256;            /* f4 idx; row=e>>4, col4=e&15 */
        int row = e >> 4, c4 = e & 15;
        float4 vv = *(const float4*)(zb + (size_t)e * 4);
        vv.x = fmaxf(vv.x * sc + sh, 0.f);
        vv.y = fmaxf(vv.y * sc + sh, 0.f);
        vv.z = fmaxf(vv.z * sc + sh, 0.f);
        vv.w = fmaxf(vv.w * sc + sh, 0.f);
        *(float4*)&Hs[row][c4 * 4] = vv;
    }
    __syncthreads();
    int wg = t & 15;       /* w = wg*4 + j */
    int tg = t >> 4;       /* rows tg + 16*i : distinct bank quads within a wave */
    float acc[8][4] = {};
    #pragma unroll
    for (int v0 = 0; v0 < 64; v0 += 4) {
        float4 a0 = *(const float4*)&As[v0 + 0][wg * 4];
        float4 a1 = *(const float4*)&As[v0 + 1][wg * 4];
        float4 a2 = *(const float4*)&As[v0 + 2][wg * 4];
        float4 a3 = *(const float4*)&As[v0 + 3][wg * 4];
        #pragma unroll
        for (int i = 0; i < 8; i++) {
            float4 h4 = *(const float4*)&Hs[tg + 16 * i][v0];
            acc[i][0] += h4.x * a0.x + h4.y * a1.x + h4.z * a2.x + h4.w * a3.x;
            acc[i][1] += h4.x * a0.y + h4.y * a1.y + h4.z * a2.y + h4.w * a3.y;
            acc[i][2] += h4.x * a0.z + h4.y * a1.z + h4.z * a2.z + h4.w * a3.z;
            acc[i][3] += h4.x * a0.w + h4.y * a1.w + h4.z * a2.w + h4.w * a3.w;
        }
    }
    float* outb = h2 + ((size_t)b * O_ + o1) * TN;
    #pragma unroll
    for (int i = 0; i < 8; i++) {
        int row = tg + 16 * i;
        float4 r = {acc[i][0], acc[i][1], acc[i][2], acc[i][3]};
        *(float4*)(outb + (size_t)row * V_ + wg * 4) = r;
    }
}

/* out = relu(bn(u) + x), in-place on d_out (u pre-BN already there) */
__global__ __launch_bounds__(256) void k_final(float* __restrict__ out,
                                               const float* __restrict__ x,
                                               const float* __restrict__ scale,
                                               const float* __restrict__ shift) {
    size_t i4 = (size_t)blockIdx.x * 256 + threadIdx.x;   /* 8388608 f4 */
    int o = (int)((i4 >> 11) & 255);                      /* 2048 f4 per (b,o) row */
    float4 u  = ((const float4*)out)[i4];
    float4 xv = ((const float4*)x)[i4];
    float sc = scale[o], sh = shift[o];
    u.x = fmaxf(u.x * sc + sh + xv.x, 0.f);
    u.y = fmaxf(u.y * sc + sh + xv.y, 0.f);
    u.z = fmaxf(u.z * sc + sh + xv.z, 0.f);
    u.w = fmaxf(u.w * sc + sh + xv.w, 0.f);
    ((float4*)out)[i4] = u;
}

extern "C" void kernel_launch(void* const* d_in, const int* in_sizes, int n_in,
                              void* d_out, int out_size, void* d_ws, size_t ws_size,
                              hipStream_t stream) {
    const float* x          = (const float*)d_in[0];
    const float* A_param    = (const float*)d_in[1];
    const float* alphap     = (const float*)d_in[2];
    const float* betap      = (const float*)d_in[3];
    const float* w1         = (const float*)d_in[4];
    const float* b1         = (const float*)d_in[5];
    const float* w2         = (const float*)d_in[6];
    const float* b2         = (const float*)d_in[7];
    const float* stem_w     = (const float*)d_in[8];
    const float* stem_b     = (const float*)d_in[9];
    const float* stem_gamma = (const float*)d_in[10];
    const float* stem_beta  = (const float*)d_in[11];
    const float* head_w     = (const float*)d_in[12];
    const float* head_b     = (const float*)d_in[13];
    const float* head_gamma = (const float*)d_in[14];
    const float* head_beta  = (const float*)d_in[15];

    float* W     = (float*)d_ws;
    float* tp    = W + OFF_TP;
    float* x1b   = W + OFF_X1;
    float* x2b   = W + OFF_X2;
    float* adab  = W + OFF_ADA;
    float* ssum  = W + OFF_STATS;
    float* ssq   = W + OFF_STATS + 256;
    float* hsum  = W + OFF_STATS + 512;
    float* hsq   = W + OFF_STATS + 768;
    float* sscale = W + OFF_SSC;
    float* sshift = W + OFF_SSC + 256;
    float* hscale = W + OFF_HSC;
    float* hshift = W + OFF_HSC + 256;
    float* zbuf  = W + OFF_Z;
    float* h2buf = W + OFF_H2;
    float* uout  = (float*)d_out;

    hipMemsetAsync(ssum, 0, 1024 * sizeof(float), stream);

    k_mean_t<<<256, 256, 0, stream>>>(x, tp);
    k_x1x2<<<256, 256, 0, stream>>>(tp, w1, b1, w2, b2, x1b, x2b);
    k_ada<<<8192, 64, 0, stream>>>(x1b, x2b, adab);
    k_gemm_stats<<<dim3(64, 4, 16), 256, 0, stream>>>(x, stem_w, stem_b, zbuf, ssum, ssq);
    k_finalize<<<1, 256, 0, stream>>>(ssum, ssq, stem_gamma, stem_beta, sscale, sshift);
    k_einsum<<<4096, 256, 0, stream>>>(zbuf, x1b, x2b, adab, A_param, alphap, betap,
                                       sscale, sshift, h2buf);
    k_gemm_stats<<<dim3(64, 4, 16), 256, 0, stream>>>(h2buf, head_w, head_b, uout, hsum, hsq);
    k_finalize<<<1, 256, 0, stream>>>(hsum, hsq, head_gamma, head_beta, hscale, hshift);
    k_final<<<32768, 256, 0, stream>>>(uout, x, hscale, hshift);
}

// Round 2
// 757.431 us; speedup vs baseline: 1.3255x; 1.3255x over previous
//
#include <hip/hip_runtime.h>
#include <cstdint>
#include <cstddef>

#define B_ 16
#define C_ 256
#define T_ 128
#define V_ 64
#define K_ 8
#define O_ 256
#define TN 8192      /* T_*V_ */
#define NBT 131072   /* B_*T_*V_ : BN sample count */

typedef unsigned short ushort_t;
typedef __attribute__((ext_vector_type(8))) short short8;
typedef __attribute__((ext_vector_type(4))) float f32x4;

/* ---- workspace layout (float offsets), total 68421632 f32 = 273.7 MB (same as round 1) ---- */
#define OFF_TP     0          /* [B][C][V] 262144; after x1x2 done, reused for w-images (bf16) */
#define OFF_X1     262144
#define OFF_X2     524288
#define OFF_STATS  786432     /* ssum,ssq,hsum,hsq 4*256 */
#define OFF_SSC    787456     /* stem scale/shift 512 */
#define OFF_HSC    787968
#define OFF_ADA    788480     /* [B][K][V][V] 524288 */
#define OFF_Z      1312768    /* [B][O][TN] fp32 33554432 ; later aliased by h2T image (bf16) */
#define OFF_H2     34867200   /* [B][O][TN] fp32 33554432 */

__device__ inline ushort_t f2bf(float f) {
    unsigned u = __builtin_bit_cast(unsigned, f);
    unsigned r = (u + 0x7FFFu + ((u >> 16) & 1u)) >> 16;
    return (ushort_t)r;
}
__device__ inline unsigned pack2(float a, float b) {
    return (unsigned)f2bf(a) | ((unsigned)f2bf(b) << 16);
}
__device__ inline void gload_lds16(const void* g, void* l) {
    __builtin_amdgcn_global_load_lds((const __attribute__((address_space(1))) unsigned int*)g,
                                     (__attribute__((address_space(3))) unsigned int*)l, 16, 0, 0);
}

/* partial mean over t (16 t's per block.y), scaled 1/T, atomic into zeroed tp */
__global__ __launch_bounds__(256) void k_meanp(const float* __restrict__ x,
                                               float* __restrict__ tp) {
    int i4 = blockIdx.x * 256 + threadIdx.x;   /* 65536 f4 outputs */
    int t0 = blockIdx.y * 16;
    int v4 = i4 & 15;
    int c  = (i4 >> 4) & 255;
    int b  = i4 >> 12;
    const float4* px = (const float4*)(x + (size_t)(b * C_ + c) * TN) + v4;
    float4 s = {0.f, 0.f, 0.f, 0.f};
    for (int t = t0; t < t0 + 16; t++) {
        float4 v = px[t * 16];
        s.x += v.x; s.y += v.y; s.z += v.z; s.w += v.w;
    }
    const float r = 1.0f / (float)T_;
    float* dst = tp + (size_t)(b * C_ + c) * V_ + v4 * 4;
    atomicAdd(&dst[0], s.x * r); atomicAdd(&dst[1], s.y * r);
    atomicAdd(&dst[2], s.z * r); atomicAdd(&dst[3], s.w * r);
}

/* x1/x2 partials over 64-c chunk, atomic into zeroed x1/x2; bias added by chunk 0 */
__global__ __launch_bounds__(256) void k_x1x2a(const float* __restrict__ tp,
                                               const float* __restrict__ w1, const float* __restrict__ b1,
                                               const float* __restrict__ w2, const float* __restrict__ b2,
                                               float* __restrict__ x1, float* __restrict__ x2) {
    int og = blockIdx.x, cc = blockIdx.y, b = blockIdx.z;
    int o  = og * 16 + (threadIdx.x >> 4);
    int v4 = threadIdx.x & 15;
    const float4* ptp = (const float4*)(tp + (size_t)b * C_ * V_) + v4;
    float4 s1 = {0.f,0.f,0.f,0.f}, s2 = {0.f,0.f,0.f,0.f};
    int c0 = cc * 64;
    for (int c = c0; c < c0 + 64; c++) {
        float4 tv = ptp[c * 16];
        float wa = w1[o * C_ + c];
        float wb = w2[o * C_ + c];
        s1.x += tv.x * wa; s1.y += tv.y * wa; s1.z += tv.z * wa; s1.w += tv.w * wa;
        s2.x += tv.x * wb; s2.y += tv.y * wb; s2.z += tv.z * wb; s2.w += tv.w * wb;
    }
    if (cc == 0) {
        float bv1 = b1[o], bv2 = b2[o];
        s1.x += bv1; s1.y += bv1; s1.z += bv1; s1.w += bv1;
        s2.x += bv2; s2.y += bv2; s2.z += bv2; s2.w += bv2;
    }
    float* p1 = x1 + (size_t)(b * O_ + o) * V_ + v4 * 4;
    float* p2 = x2 + (size_t)(b * O_ + o) * V_ + v4 * 4;
    atomicAdd(&p1[0], s1.x); atomicAdd(&p1[1], s1.y); atomicAdd(&p1[2], s1.z); atomicAdd(&p1[3], s1.w);
    atomicAdd(&p2[0], s2.x); atomicAdd(&p2[1], s2.y); atomicAdd(&p2[2], s2.z); atomicAdd(&p2[3], s2.w);
}

/* ada[b,k,v,w] = softmax_v( sum_c x1[b,k,c,v]*x2[b,k,c,w] )   one wave per (b,k,w) */
__global__ __launch_bounds__(64) void k_ada(const float* __restrict__ x1,
                                            const float* __restrict__ x2,
                                            float* __restrict__ ada) {
    int bid = blockIdx.x;
    int w = bid & 63;
    int k = (bid >> 6) & 7;
    int b = bid >> 9;
    int v = threadIdx.x;
    const float* p1 = x1 + ((size_t)b * O_ + k * 32) * V_;
    const float* p2 = x2 + ((size_t)b * O_ + k * 32) * V_;
    float s = 0.f;
    #pragma unroll
    for (int c = 0; c < 32; c++) s += p1[c * V_ + v] * p2[c * V_ + w];
    float m = s;
    #pragma unroll
    for (int off = 32; off >= 1; off >>= 1) m = fmaxf(m, __shfl_xor(m, off, 64));
    float e = __expf(s - m);
    float sum = e;
    #pragma unroll
    for (int off = 32; off >= 1; off >>= 1) sum += __shfl_xor(sum, off, 64);
    ada[((size_t)(b * K_ + k) * V_ + v) * V_ + w] = e / sum;
}

/* w[256][256] fp32 -> bf16 image: [cc 8][q 4][ol 256][cl 8], c = cc*32+q*8+cl */
__global__ __launch_bounds__(256) void k_wconv(const float* __restrict__ w,
                                               ushort_t* __restrict__ img) {
    int flat = blockIdx.x * 256 + threadIdx.x;   /* 4096 threads, 16 el each */
    #pragma unroll
    for (int g2 = 0; g2 < 2; g2++) {
        int gi = flat * 2 + g2;                  /* 8192 groups of 8 */
        int cc = gi >> 10;
        int q  = (gi >> 8) & 3;
        int ol = gi & 255;
        int c0 = cc * 32 + q * 8;
        const float* src = w + (size_t)ol * C_ + c0;
        float4 f0 = *(const float4*)src;
        float4 f1 = *(const float4*)(src + 4);
        uint4 u;
        u.x = pack2(f0.x, f0.y); u.y = pack2(f0.z, f0.w);
        u.z = pack2(f1.x, f1.y); u.w = pack2(f1.z, f1.w);
        *(uint4*)(img + (size_t)gi * 8) = u;
    }
}

/* src [b][256][8192] fp32 -> bf16 frag-image: per (b, nblk=t, cc): [q 4][nl 64][cl 8]
   element (b, n = t*64+v, c): base=((b*128+t)*8+cc)*2048, off=q*512+v*8+cl */
__global__ __launch_bounds__(256) void k_xpose(const float* __restrict__ src,
                                               ushort_t* __restrict__ img) {
    __shared__ float Lt[64][65];
    int t  = blockIdx.x;
    int cg = blockIdx.y;         /* 4 groups of 64 c */
    int b  = blockIdx.z;
    int tid = threadIdx.x;
    int c0 = cg * 64;
    #pragma unroll
    for (int i = 0; i < 4; i++) {
        int e = tid + i * 256;               /* f4 idx over 64c x 16v4 */
        int ci = e >> 4, v4 = e & 15;
        float4 v = *(const float4*)(src + ((size_t)(b * C_ + c0 + ci) * 128 + t) * 64 + v4 * 4);
        *(float4*)&Lt[ci][v4 * 4] = v;
    }
    __syncthreads();
    #pragma unroll
    for (int i = 0; i < 2; i++) {
        int p = tid + i * 256;               /* 512 pieces of 8 el */
        int v = p & 63;
        int q = (p >> 6) & 3;
        int cc2 = p >> 8;
        int cl0 = cc2 * 32 + q * 8;
        uint4 u;
        u.x = pack2(Lt[cl0 + 0][v], Lt[cl0 + 1][v]);
        u.y = pack2(Lt[cl0 + 2][v], Lt[cl0 + 3][v]);
        u.z = pack2(Lt[cl0 + 4][v], Lt[cl0 + 5][v]);
        u.w = pack2(Lt[cl0 + 6][v], Lt[cl0 + 7][v]);
        int cc = cg * 2 + cc2;
        size_t dst = ((size_t)(b * 128 + t) * 8 + cc) * 2048 + q * 512 + v * 8;
        *(uint4*)(img + dst) = u;
    }
}

/* out[b][o][n] = sum_c W[o][c] X[b][n][c] + bias[o], fp32 out.
   block: full O=256 (4 waves x 64 o), 64 n; grid (nblk 128, 1, b 16) */
__global__ __launch_bounds__(256) void k_gemm(const ushort_t* __restrict__ ximg,
                                              const ushort_t* __restrict__ wimg,
                                              const float* __restrict__ bias,
                                              float* __restrict__ out) {
    __shared__ __align__(16) ushort_t sh[2048];   /* X chunk: [q 4][nl 64][cl 8] */
    int tid = threadIdx.x;
    int nblk = blockIdx.x, b = blockIdx.z;
    int wm = tid >> 6;
    int lane = tid & 63, ln = lane & 15, q = lane >> 4;
    f32x4 acc[4][4];
    #pragma unroll
    for (int mt = 0; mt < 4; mt++)
        #pragma unroll
        for (int nt = 0; nt < 4; nt++) acc[mt][nt] = (f32x4){0.f, 0.f, 0.f, 0.f};
    const ushort_t* xbase = ximg + ((size_t)(b * 128 + nblk) * 8) * 2048;
    for (int cc = 0; cc < 8; cc++) {
        gload_lds16(xbase + (size_t)cc * 2048 + wm * 512 + lane * 8, &sh[wm * 512]);
        __syncthreads();
        short8 a[4], bb[4];
        const ushort_t* wc = wimg + (size_t)cc * 8192 + q * 2048;
        #pragma unroll
        for (int mt = 0; mt < 4; mt++)
            a[mt] = *(const short8*)(wc + (wm * 64 + mt * 16 + ln) * 8);
        #pragma unroll
        for (int nt = 0; nt < 4; nt++)
            bb[nt] = *(const short8*)&sh[q * 512 + (nt * 16 + ln) * 8];
        #pragma unroll
        for (int mt = 0; mt < 4; mt++)
            #pragma unroll
            for (int nt = 0; nt < 4; nt++)
                acc[mt][nt] = __builtin_amdgcn_mfma_f32_16x16x32_bf16(a[mt], bb[nt], acc[mt][nt], 0, 0, 0);
        __syncthreads();
    }
    int n_base = nblk * 64;
    #pragma unroll
    for (int mt = 0; mt < 4; mt++) {
        int o0 = wm * 64 + mt * 16 + q * 4;
        #pragma unroll
        for (int r = 0; r < 4; r++) {
            float bv = bias[o0 + r];
            float* orow = out + ((size_t)(b * O_ + o0 + r)) * TN + n_base + ln;
            #pragma unroll
            for (int nt = 0; nt < 4; nt++)
                orow[nt * 16] = acc[mt][nt][r] + bv;
        }
    }
}

/* per-channel sum/sumsq over one [b][o] row of 8192 fp32 */
__global__ __launch_bounds__(256) void k_stats(const float* __restrict__ src,
                                               float* __restrict__ psum,
                                               float* __restrict__ psumsq) {
    __shared__ float s_s[4], s_q[4];
    int bid = blockIdx.x;         /* 4096 = B*O */
    int o = bid & 255;
    const float4* row = (const float4*)(src + (size_t)bid * TN);
    float s = 0.f, sq = 0.f;
    #pragma unroll
    for (int i = 0; i < 8; i++) {
        float4 v = row[threadIdx.x + i * 256];
        s  += v.x + v.y + v.z + v.w;
        sq += v.x * v.x + v.y * v.y + v.z * v.z + v.w * v.w;
    }
    #pragma unroll
    for (int off = 32; off >= 1; off >>= 1) {
        s  += __shfl_xor(s,  off, 64);
        sq += __shfl_xor(sq, off, 64);
    }
    if ((threadIdx.x & 63) == 0) { s_s[threadIdx.x >> 6] = s; s_q[threadIdx.x >> 6] = sq; }
    __syncthreads();
    if (threadIdx.x == 0) {
        atomicAdd(&psum[o],   s_s[0] + s_s[1] + s_s[2] + s_s[3]);
        atomicAdd(&psumsq[o], s_q[0] + s_q[1] + s_q[2] + s_q[3]);
    }
}

__global__ void k_finalize(const float* __restrict__ psum, const float* __restrict__ psumsq,
                           const float* __restrict__ gamma, const float* __restrict__ betap,
                           float* __restrict__ scale, float* __restrict__ shift) {
    int o = threadIdx.x;
    float mean = psum[o]   * (1.0f / (float)NBT);
    float var  = psumsq[o] * (1.0f / (float)NBT) - mean * mean;
    float sc = gamma[o] * rsqrtf(var + 1e-5f);
    scale[o] = sc;
    shift[o] = betap[o] - mean * sc;
}

/* h2[b, k*32+c, t, w] = sum_v relu(bn(z[b,k*32+c,t,v])) * A[b,k,c,v,w]; A built on the fly */
__global__ __launch_bounds__(256) void k_einsum(const float* __restrict__ z,
                                                const float* __restrict__ x1,
                                                const float* __restrict__ x2,
                                                const float* __restrict__ ada,
                                                const float* __restrict__ A_param,
                                                const float* __restrict__ alphap,
                                                const float* __restrict__ betap,
                                                const float* __restrict__ scale,
                                                const float* __restrict__ shift,
                                                float* __restrict__ h2) {
    __shared__ float As[64][64];
    __shared__ float Hs[128][68];
    __shared__ float x1s[64], x2s[64];
    int t = threadIdx.x;
    int c = blockIdx.x & 31;
    int k = (blockIdx.x >> 5) & 7;
    int b = blockIdx.x >> 8;
    int o1 = k * 32 + c;
    float alpha = alphap[0], beta = betap[0];
    if (t < 64)        x1s[t]      = x1[((size_t)b * O_ + o1) * V_ + t];
    else if (t < 128)  x2s[t - 64] = x2[((size_t)b * O_ + o1) * V_ + (t - 64)];
    __syncthreads();
    const float* adab = ada + (size_t)(b * K_ + k) * V_ * V_;
    const float* Apb  = A_param + (size_t)k * V_ * V_;
    #pragma unroll
    for (int i = 0; i < 16; i++) {
        int e = t + i * 256;
        int v = e >> 6, w = e & 63;
        As[v][w] = Apb[e] + alpha * tanhf(x1s[v] - x2s[w]) + beta * adab[e];
    }
    float sc = scale[o1], sh = shift[o1];
    const float* zb = z + ((size_t)b * O_ + o1) * TN;
    #pragma unroll
    for (int i = 0; i < 8; i++) {
        int e = t + i * 256;
        int row = e >> 4, c4 = e & 15;
        float4 vv = *(const float4*)(zb + (size_t)e * 4);
        vv.x = fmaxf(vv.x * sc + sh, 0.f);
        vv.y = fmaxf(vv.y * sc + sh, 0.f);
        vv.z = fmaxf(vv.z * sc + sh, 0.f);
        vv.w = fmaxf(vv.w * sc + sh, 0.f);
        *(float4*)&Hs[row][c4 * 4] = vv;
    }
    __syncthreads();
    int wg = t & 15;
    int tg = t >> 4;
    float acc[8][4] = {};
    #pragma unroll
    for (int v0 = 0; v0 < 64; v0 += 4) {
        float4 a0 = *(const float4*)&As[v0 + 0][wg * 4];
        float4 a1 = *(const float4*)&As[v0 + 1][wg * 4];
        float4 a2 = *(const float4*)&As[v0 + 2][wg * 4];
        float4 a3 = *(const float4*)&As[v0 + 3][wg * 4];
        #pragma unroll
        for (int i = 0; i < 8; i++) {
            float4 h4 = *(const float4*)&Hs[tg + 16 * i][v0];
            acc[i][0] += h4.x * a0.x + h4.y * a1.x + h4.z * a2.x + h4.w * a3.x;
            acc[i][1] += h4.x * a0.y + h4.y * a1.y + h4.z * a2.y + h4.w * a3.y;
            acc[i][2] += h4.x * a0.z + h4.y * a1.z + h4.z * a2.z + h4.w * a3.z;
            acc[i][3] += h4.x * a0.w + h4.y * a1.w + h4.z * a2.w + h4.w * a3.w;
        }
    }
    float* outb = h2 + ((size_t)b * O_ + o1) * TN;
    #pragma unroll
    for (int i = 0; i < 8; i++) {
        int row = tg + 16 * i;
        float4 r = {acc[i][0], acc[i][1], acc[i][2], acc[i][3]};
        *(float4*)(outb + (size_t)row * V_ + wg * 4) = r;
    }
}

/* out = relu(bn(u) + x), in-place on d_out */
__global__ __launch_bounds__(256) void k_final(float* __restrict__ out,
                                               const float* __restrict__ x,
                                               const float* __restrict__ scale,
                                               const float* __restrict__ shift) {
    size_t i4 = (size_t)blockIdx.x * 256 + threadIdx.x;
    int o = (int)((i4 >> 11) & 255);
    float4 u  = ((const float4*)out)[i4];
    float4 xv = ((const float4*)x)[i4];
    float sc = scale[o], sh = shift[o];
    u.x = fmaxf(u.x * sc + sh + xv.x, 0.f);
    u.y = fmaxf(u.y * sc + sh + xv.y, 0.f);
    u.z = fmaxf(u.z * sc + sh + xv.z, 0.f);
    u.w = fmaxf(u.w * sc + sh + xv.w, 0.f);
    ((float4*)out)[i4] = u;
}

extern "C" void kernel_launch(void* const* d_in, const int* in_sizes, int n_in,
                              void* d_out, int out_size, void* d_ws, size_t ws_size,
                              hipStream_t stream) {
    const float* x          = (const float*)d_in[0];
    const float* A_param    = (const float*)d_in[1];
    const float* alphap     = (const float*)d_in[2];
    const float* betap      = (const float*)d_in[3];
    const float* w1         = (const float*)d_in[4];
    const float* b1         = (const float*)d_in[5];
    const float* w2         = (const float*)d_in[6];
    const float* b2         = (const float*)d_in[7];
    const float* stem_w     = (const float*)d_in[8];
    const float* stem_b     = (const float*)d_in[9];
    const float* stem_gamma = (const float*)d_in[10];
    const float* stem_beta  = (const float*)d_in[11];
    const float* head_w     = (const float*)d_in[12];
    const float* head_b     = (const float*)d_in[13];
    const float* head_gamma = (const float*)d_in[14];
    const float* head_beta  = (const float*)d_in[15];

    float* W      = (float*)d_ws;
    float* tp     = W + OFF_TP;
    float* x1b    = W + OFF_X1;
    float* x2b    = W + OFF_X2;
    float* ssum   = W + OFF_STATS;
    float* ssq    = W + OFF_STATS + 256;
    float* hsum   = W + OFF_STATS + 512;
    float* hsq    = W + OFF_STATS + 768;
    float* sscale = W + OFF_SSC;
    float* sshift = W + OFF_SSC + 256;
    float* hscale = W + OFF_HSC;
    float* hshift = W + OFF_HSC + 256;
    float* adab   = W + OFF_ADA;
    float* zbuf   = W + OFF_Z;
    float* h2buf  = W + OFF_H2;
    float* uout   = (float*)d_out;

    /* scratch aliases (lifetime-checked):
       xTimg  -> d_out (dead before head GEMM writes d_out)
       wimgs  -> tp region (written after x1x2 is done with tp)
       h2Timg -> z region (z dead after einsum) */
    ushort_t* xTimg  = (ushort_t*)d_out;
    ushort_t* wsimg  = (ushort_t*)(W + OFF_TP);            /* 65536 bf16 = 32768 f32 */
    ushort_t* whimg  = (ushort_t*)(W + OFF_TP + 32768);
    ushort_t* h2Timg = (ushort_t*)(W + OFF_Z);

    /* zero tp, x1, x2, stats (atomic accumulation targets) */
    hipMemsetAsync(W, 0, (size_t)(OFF_STATS + 1024) * sizeof(float), stream);

    k_meanp<<<dim3(256, 8), 256, 0, stream>>>(x, tp);
    k_x1x2a<<<dim3(16, 4, 16), 256, 0, stream>>>(tp, w1, b1, w2, b2, x1b, x2b);
    k_ada<<<8192, 64, 0, stream>>>(x1b, x2b, adab);
    /* tp is dead now: write weight images into its space */
    k_wconv<<<16, 256, 0, stream>>>(stem_w, wsimg);
    k_wconv<<<16, 256, 0, stream>>>(head_w, whimg);
    k_xpose<<<dim3(128, 4, 16), 256, 0, stream>>>(x, xTimg);

    k_gemm<<<dim3(128, 1, 16), 256, 0, stream>>>(xTimg, wsimg, stem_b, zbuf);
    k_stats<<<4096, 256, 0, stream>>>(zbuf, ssum, ssq);
    k_finalize<<<1, 256, 0, stream>>>(ssum, ssq, stem_gamma, stem_beta, sscale, sshift);

    k_einsum<<<4096, 256, 0, stream>>>(zbuf, x1b, x2b, adab, A_param, alphap, betap,
                                       sscale, sshift, h2buf);
    /* z dead: transpose h2 into its space */
    k_xpose<<<dim3(128, 4, 16), 256, 0, stream>>>(h2buf, h2Timg);

    k_gemm<<<dim3(128, 1, 16), 256, 0, stream>>>(h2Timg, whimg, head_b, uout);
    k_stats<<<4096, 256, 0, stream>>>(uout, hsum, hsq);
    k_finalize<<<1, 256, 0, stream>>>(hsum, hsq, head_gamma, head_beta, hscale, hshift);
    k_final<<<32768, 256, 0, stream>>>(uout, x, hscale, hshift);
}